// Round 12
// baseline (126.195 us; speedup 1.0000x reference)
//
#include <hip/hip_runtime.h>
#include <hip/hip_bf16.h>

#define N_TOK 65536
#define KCB   512
#define DIM   64
#define TPB   32    // tokens per block

typedef __attribute__((ext_vector_type(8)))  short s16x8;
typedef __attribute__((ext_vector_type(16))) float f32x16;
typedef unsigned long long u64;

__device__ __forceinline__ unsigned bf16rne(float f) {
  unsigned u = __float_as_uint(f);
  return (u + 0x7FFFu + ((u >> 16) & 1u)) >> 16;   // round-to-nearest-even
}
__device__ __forceinline__ unsigned bf2(float lo, float hi) {
  return bf16rne(lo) | (bf16rne(hi) << 16);
}
__device__ __forceinline__ float bfback(float x) {  // RNE16(x) as f32
  return __uint_as_float(bf16rne(x) << 16);
}
// lo-residual pair: RNE16(x - RNE16(x))
__device__ __forceinline__ unsigned bf2lo(float x, float y) {
  return bf2(x - bfback(x), y - bfback(y));
}
// Monotone f32->u32: unsigned compare == float compare (total order).
__device__ __forceinline__ unsigned mono(float f) {
  unsigned u = __float_as_uint(f);
  return u ^ ((unsigned)((int)u >> 31) | 0x80000000u);
}
__device__ __forceinline__ u64 u64min(u64 a, u64 b) { return a < b ? a : b; }

// Prep: codebook -> fragment-major HI and LO bf16 sets + csq.
__global__ __launch_bounds__(256) void vq_prep_kernel(
    const float* __restrict__ cb, uint4* __restrict__ cb_frag,
    float* __restrict__ csqg) {
  const int gid = blockIdx.x * 256 + threadIdx.x;
  if (gid < 4096) {                       // 16 RT x 4 s x 64 lanes
    const int f = gid >> 6, lane = gid & 63;
    const int RT = f >> 2, s = f & 3;
    const int row = RT * 32 + (lane & 31);
    const float4* src =
        reinterpret_cast<const float4*>(cb + (size_t)row * DIM + s * 16 + (lane >> 5) * 8);
    const float4 a = src[0], b = src[1];
    cb_frag[gid] = make_uint4(bf2(a.x, a.y), bf2(a.z, a.w), bf2(b.x, b.y), bf2(b.z, b.w));
    cb_frag[4096 + gid] =
        make_uint4(bf2lo(a.x, a.y), bf2lo(a.z, a.w), bf2lo(b.x, b.y), bf2lo(b.z, b.w));
  } else if (gid < 4096 + KCB) {
    const int k = gid - 4096;
    const float4* r4 = reinterpret_cast<const float4*>(cb + (size_t)k * DIM);
    float s = 0.f;
#pragma unroll
    for (int i = 0; i < 16; ++i) {
      float4 c = r4[i];
      s = fmaf(c.x, c.x, s); s = fmaf(c.y, c.y, s);
      s = fmaf(c.z, c.z, s); s = fmaf(c.w, c.w, s);
    }
    csqg[k] = s;
  }
}

// Single-pass split-precision certified argmin + fused gather.
// dot = hiA*hiB (+hiA*loB in acc1) + loA*hiB: |S - S_f32| <= marg/2.
// Pass A tracks (m1,k1,m2) online; margin-resolved tokens (99.6%) are
// FINAL with no second pass. Unresolved -> full exact f32 scan (rare).
// No candidate lists, no atomics, no state alive across phases but LDS.
__global__ __launch_bounds__(256, 6) void vq_argmin_kernel(
    const float* __restrict__ cb,
    const float* __restrict__ emb,
    const uint4* __restrict__ cb_frag,
    const float* __restrict__ csqg,
    float* __restrict__ out) {
  __shared__ char  etile[TPB * 128];     // 4 KB swizzled bf16 hi tokens
  __shared__ char  etilo[TPB * 128];     // 4 KB swizzled bf16 lo tokens
  __shared__ float csq_l[KCB];           // 2 KB
  __shared__ float esq_p[256];           // 1 KB (8 partials per token)
  __shared__ float mA[4][TPB];           // per-wave m1
  __shared__ float mB[4][TPB];           // per-wave m2
  __shared__ int   kA[4][TPB];           // per-wave k1
  __shared__ int   sel[TPB];
  __shared__ int   needR[TPB];

  const int tid  = threadIdx.x;
  const int lane = tid & 63;
  const int w    = tid >> 6;
  const int col  = lane & 31;            // token within block
  const int half = lane >> 5;
  const int blk  = blockIdx.x;

  // ---- stage 32 tokens: 8 f32/thread -> hi + lo bf16 swizzled LDS ----
  {
    const float4* ep4 = reinterpret_cast<const float4*>(emb + (size_t)blk * TPB * DIM);
    const float4 v0 = ep4[tid * 2 + 0], v1 = ep4[tid * 2 + 1];
    float ss = 0.f;
    ss = fmaf(v0.x, v0.x, ss); ss = fmaf(v0.y, v0.y, ss);
    ss = fmaf(v0.z, v0.z, ss); ss = fmaf(v0.w, v0.w, ss);
    ss = fmaf(v1.x, v1.x, ss); ss = fmaf(v1.y, v1.y, ss);
    ss = fmaf(v1.z, v1.z, ss); ss = fmaf(v1.w, v1.w, ss);
    esq_p[tid] = ss;
    const int tok = tid >> 3, c0 = tid & 7;        // 16B bf16 chunk c0
    const int a0 = tok * 128 + ((16 * c0) ^ ((tok & 7) << 4));
    *reinterpret_cast<uint4*>(etile + a0) =
        make_uint4(bf2(v0.x, v0.y), bf2(v0.z, v0.w), bf2(v1.x, v1.y), bf2(v1.z, v1.w));
    *reinterpret_cast<uint4*>(etilo + a0) =
        make_uint4(bf2lo(v0.x, v0.y), bf2lo(v0.z, v0.w), bf2lo(v1.x, v1.y), bf2lo(v1.z, v1.w));
  }
  if (tid < 128)
    reinterpret_cast<float4*>(csq_l)[tid] = reinterpret_cast<const float4*>(csqg)[tid];
  __syncthreads();                                          // barrier 1

  // ---- B-fragment preload: hi + lo (8 ds_read_b128 per lane) ----
  s16x8 Bh[4], Bl[4];
#pragma unroll
  for (int s = 0; s < 4; ++s) {
    const int c = 2 * s + half;
    const int a = col * 128 + ((16 * c) ^ ((col & 7) << 4));
    Bh[s] = *reinterpret_cast<const s16x8*>(etile + a);
    Bl[s] = *reinterpret_cast<const s16x8*>(etilo + a);
  }

  const int rowbase = w * 128;
  const s16x8* frag = reinterpret_cast<const s16x8*>(cb_frag);
  const s16x8* fragLo = frag + 4096;

  // ---- Pass A: split MFMA -> online (m1,k1,m2); accs die per tile ----
  float m1 = 3.4e38f, m2 = 3.4e38f;
  int k1 = 0;
#pragma unroll
  for (int rt = 0; rt < 4; ++rt) {
    const int fb = ((w * 4 + rt) * 4) * 64 + lane;
    f32x16 a0 = {}, a1 = {};                 // 2 accs break the MFMA chain
#pragma unroll
    for (int s = 0; s < 4; ++s) {
      const s16x8 Ah = frag[fb + s * 64];    // streamed, dies after 2 MFMAs
      a0 = __builtin_amdgcn_mfma_f32_32x32x16_bf16(Ah, Bh[s], a0, 0, 0, 0);
      a1 = __builtin_amdgcn_mfma_f32_32x32x16_bf16(Ah, Bl[s], a1, 0, 0, 0);
      const s16x8 Al = fragLo[fb + s * 64];
      a0 = __builtin_amdgcn_mfma_f32_32x32x16_bf16(Al, Bh[s], a0, 0, 0, 0);
    }
    const int rb = rowbase + rt * 32 + 4 * half;
#pragma unroll
    for (int gq = 0; gq < 4; ++gq) {
      const float4 cs = *reinterpret_cast<const float4*>(&csq_l[rb + 8 * gq]);
#pragma unroll
      for (int e = 0; e < 4; ++e) {
        const float c = (e == 0) ? cs.x : (e == 1) ? cs.y : (e == 2) ? cs.z : cs.w;
        const float S = fmaf(-2.f, a0[gq * 4 + e], fmaf(-2.f, a1[gq * 4 + e], c));
        const float tmx = fmaxf(m1, S);      // m2 update BEFORE m1
        m2 = fminf(m2, tmx);
        const bool lt = S < m1;              // k ascends: strict < keeps low k
        k1 = lt ? (rb + 8 * gq + e) : k1;
        m1 = fminf(m1, S);
      }
    }
  }
  // wave-half merge (halves interleave rows: explicit k tie-break)
  {
    const float m1o = __shfl_xor(m1, 32);
    const float m2o = __shfl_xor(m2, 32);
    const int k1o = __shfl_xor(k1, 32);
    const float tmx = fmaxf(m1, m1o);
    m2 = fminf(fminf(m2, m2o), tmx);
    const bool better = (m1o < m1) || (m1o == m1 && k1o < k1);
    k1 = better ? k1o : k1;
    m1 = fminf(m1, m1o);
  }
  if (lane < 32) { mA[w][col] = m1; mB[w][col] = m2; kA[w][col] = k1; }
  __syncthreads();                                          // barrier 2

  // ---- block merge + margin certification (tid<TPB only) ----
  if (tid < TPB) {
    float bm1 = mA[0][tid], bm2 = mB[0][tid];
    int bk = kA[0][tid];
#pragma unroll
    for (int w2 = 1; w2 < 4; ++w2) {
      const float om1 = mA[w2][tid], om2 = mB[w2][tid];
      const int ok = kA[w2][tid];
      const float tmx = fmaxf(bm1, om1);
      bm2 = fminf(fminf(bm2, om2), tmx);
      if (om1 < bm1) bk = ok;                // disjoint ascending k ranges
      bm1 = fminf(bm1, om1);
    }
    const float esq = ((esq_p[tid * 8 + 0] + esq_p[tid * 8 + 1]) +
                      (esq_p[tid * 8 + 2] + esq_p[tid * 8 + 3])) +
                      ((esq_p[tid * 8 + 4] + esq_p[tid * 8 + 5]) +
                      (esq_p[tid * 8 + 6] + esq_p[tid * 8 + 7]));
    const float marg = 2e-4f * sqrtf(esq) + 2e-5f;   // 2B, >2x slack
    const bool res = (bm2 - bm1) > marg;
    needR[tid] = res ? 0 : 1;
    sel[tid] = bk;
    if (res) out[(size_t)2 * N_TOK * DIM + blk * TPB + tid] = (float)bk;
  }
  __syncthreads();                                          // barrier 3

  // ---- Phase C (rare, ~0.4% tokens): full exact f32 scan, 8 lanes/token ----
  {
    const int t = tid >> 3, sub = tid & 7;
    if (needR[t]) {
      const float* erow = emb + (size_t)(blk * TPB + t) * DIM + sub * 8;
      const float4 e0 = reinterpret_cast<const float4*>(erow)[0];
      const float4 e1 = reinterpret_cast<const float4*>(erow)[1];
      u64 bb = ~0ull;
      for (int k = 0; k < KCB; ++k) {
        const float4* c4 = reinterpret_cast<const float4*>(cb + (size_t)k * DIM + sub * 8);
        const float4 c0 = c4[0], c1 = c4[1];
        float s0 = 0.f, s1 = 0.f;
        s0 = fmaf(c0.x, e0.x, s0); s1 = fmaf(c0.y, e0.y, s1);
        s0 = fmaf(c0.z, e0.z, s0); s1 = fmaf(c0.w, e0.w, s1);
        s0 = fmaf(c1.x, e1.x, s0); s1 = fmaf(c1.y, e1.y, s1);
        s0 = fmaf(c1.z, e1.z, s0); s1 = fmaf(c1.w, e1.w, s1);
        float p = s0 + s1;
        p += __shfl_xor(p, 1);
        p += __shfl_xor(p, 2);
        p += __shfl_xor(p, 4);
        const float S = fmaf(-2.f, p, csq_l[k]);
        bb = u64min(bb, ((u64)mono(S) << 32) | (unsigned)k);
      }
      if (sub == 0) {
        const int idx = (int)(unsigned)(bb & 0xFFFFFFFFull);
        sel[t] = idx;
        out[(size_t)2 * N_TOK * DIM + blk * TPB + t] = (float)idx;
      }
    }
  }
  __syncthreads();                                          // barrier 4

  // ---- Phase D: fused gather-write of both quantized sections ----
  {
    const float4* cb4 = reinterpret_cast<const float4*>(cb);
    float4* out4 = reinterpret_cast<float4*>(out);
#pragma unroll
    for (int mm = 0; mm < 2; ++mm) {
      const int i = tid + 256 * mm;
      const int t = i >> 4, j = i & 15;
      const float4 v = cb4[sel[t] * (DIM / 4) + j];
      const size_t g = (size_t)(blk * TPB + t) * (DIM / 4) + j;
      out4[g] = v;
      out4[(size_t)N_TOK * (DIM / 4) + g] = v;
    }
  }
}

extern "C" void kernel_launch(void* const* d_in, const int* in_sizes, int n_in,
                              void* d_out, int out_size, void* d_ws, size_t ws_size,
                              hipStream_t stream) {
  const float* cb  = (const float*)d_in[0];   // (512, 64) f32
  const float* emb = (const float*)d_in[1];   // (65536, 1, 64) f32
  float* out = (float*)d_out;
  uint4* cb_frag = (uint4*)d_ws;                            // 128 KB hi+lo fragments
  float* csqg = (float*)((char*)d_ws + 131072);             // 2 KB csq

  vq_prep_kernel<<<18, 256, 0, stream>>>(cb, cb_frag, csqg);
  vq_argmin_kernel<<<N_TOK / TPB, 256, 0, stream>>>(cb, emb, cb_frag, csqg, out);
}

// Round 13
// 115.731 us; speedup vs baseline: 1.0904x; 1.0904x over previous
//
#include <hip/hip_runtime.h>
#include <hip/hip_bf16.h>

#define N_TOK 65536
#define KCB   512
#define DIM   64
#define TPB   32    // tokens per block

typedef __attribute__((ext_vector_type(8)))  short s16x8;
typedef __attribute__((ext_vector_type(16))) float f32x16;
typedef unsigned long long u64;

__device__ __forceinline__ unsigned bf16rne(float f) {
  unsigned u = __float_as_uint(f);
  return (u + 0x7FFFu + ((u >> 16) & 1u)) >> 16;   // round-to-nearest-even
}
__device__ __forceinline__ unsigned bf2(float lo, float hi) {
  return bf16rne(lo) | (bf16rne(hi) << 16);
}
__device__ __forceinline__ float bfback(float x) {  // RNE16(x) as f32
  return __uint_as_float(bf16rne(x) << 16);
}
// lo-residual pair: RNE16(x - RNE16(x))
__device__ __forceinline__ unsigned bf2lo(float x, float y) {
  return bf2(x - bfback(x), y - bfback(y));
}
// Monotone f32->u32: unsigned compare == float compare (total order).
__device__ __forceinline__ unsigned mono(float f) {
  unsigned u = __float_as_uint(f);
  return u ^ ((unsigned)((int)u >> 31) | 0x80000000u);
}
__device__ __forceinline__ u64 u64min(u64 a, u64 b) { return a < b ? a : b; }

// Prep: codebook -> fragment-major HI and LO bf16 sets + csq.
__global__ __launch_bounds__(256) void vq_prep_kernel(
    const float* __restrict__ cb, uint4* __restrict__ cb_frag,
    float* __restrict__ csqg) {
  const int gid = blockIdx.x * 256 + threadIdx.x;
  if (gid < 4096) {                       // 16 RT x 4 s x 64 lanes
    const int f = gid >> 6, lane = gid & 63;
    const int RT = f >> 2, s = f & 3;
    const int row = RT * 32 + (lane & 31);
    const float4* src =
        reinterpret_cast<const float4*>(cb + (size_t)row * DIM + s * 16 + (lane >> 5) * 8);
    const float4 a = src[0], b = src[1];
    cb_frag[gid] = make_uint4(bf2(a.x, a.y), bf2(a.z, a.w), bf2(b.x, b.y), bf2(b.z, b.w));
    cb_frag[4096 + gid] =
        make_uint4(bf2lo(a.x, a.y), bf2lo(a.z, a.w), bf2lo(b.x, b.y), bf2lo(b.z, b.w));
  } else if (gid < 4096 + KCB) {
    const int k = gid - 4096;
    const float4* r4 = reinterpret_cast<const float4*>(cb + (size_t)k * DIM);
    float s = 0.f;
#pragma unroll
    for (int i = 0; i < 16; ++i) {
      float4 c = r4[i];
      s = fmaf(c.x, c.x, s); s = fmaf(c.y, c.y, s);
      s = fmaf(c.z, c.z, s); s = fmaf(c.w, c.w, s);
    }
    csqg[k] = s;
  }
}

// Single-pass split-precision certified argmin + fused gather.
// dot = hiA*hiB (+hiA*loB in acc1) + loA*hiB: |S - S_f32| <= marg/2.
// Pass A tracks (m1,k1,m2) online; margin-resolved tokens (99.6%) are
// FINAL. Unresolved -> full exact f32 scan (rare).
// launch_bounds (256,4): 128-VGPR cap — live set (Bh/Bl 32 + accs 32 +
// temps/fold ~35) fits; (256,6)'s 85-cap caused round-12's 82MB spill.
__global__ __launch_bounds__(256, 4) void vq_argmin_kernel(
    const float* __restrict__ cb,
    const float* __restrict__ emb,
    const uint4* __restrict__ cb_frag,
    const float* __restrict__ csqg,
    float* __restrict__ out) {
  __shared__ char  etile[TPB * 128];     // 4 KB swizzled bf16 hi tokens
  __shared__ char  etilo[TPB * 128];     // 4 KB swizzled bf16 lo tokens
  __shared__ float csq_l[KCB];           // 2 KB
  __shared__ float esq_p[256];           // 1 KB (8 partials per token)
  __shared__ float mA[4][TPB];           // per-wave m1
  __shared__ float mB[4][TPB];           // per-wave m2
  __shared__ int   kA[4][TPB];           // per-wave k1
  __shared__ int   sel[TPB];
  __shared__ int   needR[TPB];

  const int tid  = threadIdx.x;
  const int lane = tid & 63;
  const int w    = tid >> 6;
  const int col  = lane & 31;            // token within block
  const int half = lane >> 5;
  const int blk  = blockIdx.x;

  // ---- stage 32 tokens: 8 f32/thread -> hi + lo bf16 swizzled LDS ----
  {
    const float4* ep4 = reinterpret_cast<const float4*>(emb + (size_t)blk * TPB * DIM);
    const float4 v0 = ep4[tid * 2 + 0], v1 = ep4[tid * 2 + 1];
    float ss = 0.f;
    ss = fmaf(v0.x, v0.x, ss); ss = fmaf(v0.y, v0.y, ss);
    ss = fmaf(v0.z, v0.z, ss); ss = fmaf(v0.w, v0.w, ss);
    ss = fmaf(v1.x, v1.x, ss); ss = fmaf(v1.y, v1.y, ss);
    ss = fmaf(v1.z, v1.z, ss); ss = fmaf(v1.w, v1.w, ss);
    esq_p[tid] = ss;
    const int tok = tid >> 3, c0 = tid & 7;        // 16B bf16 chunk c0
    const int a0 = tok * 128 + ((16 * c0) ^ ((tok & 7) << 4));
    *reinterpret_cast<uint4*>(etile + a0) =
        make_uint4(bf2(v0.x, v0.y), bf2(v0.z, v0.w), bf2(v1.x, v1.y), bf2(v1.z, v1.w));
    *reinterpret_cast<uint4*>(etilo + a0) =
        make_uint4(bf2lo(v0.x, v0.y), bf2lo(v0.z, v0.w), bf2lo(v1.x, v1.y), bf2lo(v1.z, v1.w));
  }
  if (tid < 128)
    reinterpret_cast<float4*>(csq_l)[tid] = reinterpret_cast<const float4*>(csqg)[tid];
  __syncthreads();                                          // barrier 1

  // ---- B-fragment preload: hi + lo (8 ds_read_b128 per lane) ----
  s16x8 Bh[4], Bl[4];
#pragma unroll
  for (int s = 0; s < 4; ++s) {
    const int c = 2 * s + half;
    const int a = col * 128 + ((16 * c) ^ ((col & 7) << 4));
    Bh[s] = *reinterpret_cast<const s16x8*>(etile + a);
    Bl[s] = *reinterpret_cast<const s16x8*>(etilo + a);
  }

  const int rowbase = w * 128;
  const s16x8* frag = reinterpret_cast<const s16x8*>(cb_frag);
  const s16x8* fragLo = frag + 4096;

  // ---- Pass A: split MFMA -> online (m1,k1,m2); accs die per tile ----
  // unroll 1: keeps one tile's A-loads/accs live at a time (round-12 fix).
  float m1 = 3.4e38f, m2 = 3.4e38f;
  int k1 = 0;
#pragma unroll 1
  for (int rt = 0; rt < 4; ++rt) {
    const int fb = ((w * 4 + rt) * 4) * 64 + lane;
    f32x16 a0 = {}, a1 = {};                 // 2 accs break the MFMA chain
#pragma unroll
    for (int s = 0; s < 4; ++s) {
      const s16x8 Ah = frag[fb + s * 64];    // streamed, dies after 2 MFMAs
      a0 = __builtin_amdgcn_mfma_f32_32x32x16_bf16(Ah, Bh[s], a0, 0, 0, 0);
      a1 = __builtin_amdgcn_mfma_f32_32x32x16_bf16(Ah, Bl[s], a1, 0, 0, 0);
      const s16x8 Al = fragLo[fb + s * 64];
      a0 = __builtin_amdgcn_mfma_f32_32x32x16_bf16(Al, Bh[s], a0, 0, 0, 0);
    }
    const int rb = rowbase + rt * 32 + 4 * half;
#pragma unroll
    for (int gq = 0; gq < 4; ++gq) {
      const float4 cs = *reinterpret_cast<const float4*>(&csq_l[rb + 8 * gq]);
#pragma unroll
      for (int e = 0; e < 4; ++e) {
        const float c = (e == 0) ? cs.x : (e == 1) ? cs.y : (e == 2) ? cs.z : cs.w;
        const float S = fmaf(-2.f, a0[gq * 4 + e], fmaf(-2.f, a1[gq * 4 + e], c));
        const float tmx = fmaxf(m1, S);      // m2 update BEFORE m1
        m2 = fminf(m2, tmx);
        const bool lt = S < m1;              // k ascends: strict < keeps low k
        k1 = lt ? (rb + 8 * gq + e) : k1;
        m1 = fminf(m1, S);
      }
    }
  }
  // wave-half merge (halves interleave rows: explicit k tie-break)
  {
    const float m1o = __shfl_xor(m1, 32);
    const float m2o = __shfl_xor(m2, 32);
    const int k1o = __shfl_xor(k1, 32);
    const float tmx = fmaxf(m1, m1o);
    m2 = fminf(fminf(m2, m2o), tmx);
    const bool better = (m1o < m1) || (m1o == m1 && k1o < k1);
    k1 = better ? k1o : k1;
    m1 = fminf(m1, m1o);
  }
  if (lane < 32) { mA[w][col] = m1; mB[w][col] = m2; kA[w][col] = k1; }
  __syncthreads();                                          // barrier 2

  // ---- block merge + margin certification (tid<TPB only) ----
  if (tid < TPB) {
    float bm1 = mA[0][tid], bm2 = mB[0][tid];
    int bk = kA[0][tid];
#pragma unroll
    for (int w2 = 1; w2 < 4; ++w2) {
      const float om1 = mA[w2][tid], om2 = mB[w2][tid];
      const int ok = kA[w2][tid];
      const float tmx = fmaxf(bm1, om1);
      bm2 = fminf(fminf(bm2, om2), tmx);
      if (om1 < bm1) bk = ok;                // disjoint ascending k ranges
      bm1 = fminf(bm1, om1);
    }
    const float esq = ((esq_p[tid * 8 + 0] + esq_p[tid * 8 + 1]) +
                      (esq_p[tid * 8 + 2] + esq_p[tid * 8 + 3])) +
                      ((esq_p[tid * 8 + 4] + esq_p[tid * 8 + 5]) +
                      (esq_p[tid * 8 + 6] + esq_p[tid * 8 + 7]));
    const float marg = 2e-4f * sqrtf(esq) + 2e-5f;   // 2B, >2x slack
    const bool res = (bm2 - bm1) > marg;
    needR[tid] = res ? 0 : 1;
    sel[tid] = bk;
    if (res) out[(size_t)2 * N_TOK * DIM + blk * TPB + tid] = (float)bk;
  }
  __syncthreads();                                          // barrier 3

  // ---- Phase C (rare, ~0.4% tokens): full exact f32 scan, 8 lanes/token ----
  {
    const int t = tid >> 3, sub = tid & 7;
    if (needR[t]) {
      const float* erow = emb + (size_t)(blk * TPB + t) * DIM + sub * 8;
      const float4 e0 = reinterpret_cast<const float4*>(erow)[0];
      const float4 e1 = reinterpret_cast<const float4*>(erow)[1];
      u64 bb = ~0ull;
      for (int k = 0; k < KCB; ++k) {
        const float4* c4 = reinterpret_cast<const float4*>(cb + (size_t)k * DIM + sub * 8);
        const float4 c0 = c4[0], c1 = c4[1];
        float s0 = 0.f, s1 = 0.f;
        s0 = fmaf(c0.x, e0.x, s0); s1 = fmaf(c0.y, e0.y, s1);
        s0 = fmaf(c0.z, e0.z, s0); s1 = fmaf(c0.w, e0.w, s1);
        s0 = fmaf(c1.x, e1.x, s0); s1 = fmaf(c1.y, e1.y, s1);
        s0 = fmaf(c1.z, e1.z, s0); s1 = fmaf(c1.w, e1.w, s1);
        float p = s0 + s1;
        p += __shfl_xor(p, 1);
        p += __shfl_xor(p, 2);
        p += __shfl_xor(p, 4);
        const float S = fmaf(-2.f, p, csq_l[k]);
        bb = u64min(bb, ((u64)mono(S) << 32) | (unsigned)k);
      }
      if (sub == 0) {
        const int idx = (int)(unsigned)(bb & 0xFFFFFFFFull);
        sel[t] = idx;
        out[(size_t)2 * N_TOK * DIM + blk * TPB + t] = (float)idx;
      }
    }
  }
  __syncthreads();                                          // barrier 4

  // ---- Phase D: fused gather-write of both quantized sections ----
  {
    const float4* cb4 = reinterpret_cast<const float4*>(cb);
    float4* out4 = reinterpret_cast<float4*>(out);
#pragma unroll
    for (int mm = 0; mm < 2; ++mm) {
      const int i = tid + 256 * mm;
      const int t = i >> 4, j = i & 15;
      const float4 v = cb4[sel[t] * (DIM / 4) + j];
      const size_t g = (size_t)(blk * TPB + t) * (DIM / 4) + j;
      out4[g] = v;
      out4[(size_t)N_TOK * (DIM / 4) + g] = v;
    }
  }
}

extern "C" void kernel_launch(void* const* d_in, const int* in_sizes, int n_in,
                              void* d_out, int out_size, void* d_ws, size_t ws_size,
                              hipStream_t stream) {
  const float* cb  = (const float*)d_in[0];   // (512, 64) f32
  const float* emb = (const float*)d_in[1];   // (65536, 1, 64) f32
  float* out = (float*)d_out;
  uint4* cb_frag = (uint4*)d_ws;                            // 128 KB hi+lo fragments
  float* csqg = (float*)((char*)d_ws + 131072);             // 2 KB csq

  vq_prep_kernel<<<18, 256, 0, stream>>>(cb, cb_frag, csqg);
  vq_argmin_kernel<<<N_TOK / TPB, 256, 0, stream>>>(cb, emb, cb_frag, csqg, out);
}

// Round 14
// 43.662 us; speedup vs baseline: 2.8903x; 2.6506x over previous
//
#include <hip/hip_runtime.h>
#include <hip/hip_bf16.h>

#define N_TOK 65536
#define KCB   512
#define DIM   64
#define TPB   32    // tokens per block

typedef __attribute__((ext_vector_type(8)))  short s16x8;
typedef __attribute__((ext_vector_type(16))) float f32x16;
typedef unsigned long long u64;

__device__ __forceinline__ unsigned bf16rne(float f) {
  unsigned u = __float_as_uint(f);
  return (u + 0x7FFFu + ((u >> 16) & 1u)) >> 16;   // round-to-nearest-even
}
__device__ __forceinline__ unsigned bf2(float lo, float hi) {
  return bf16rne(lo) | (bf16rne(hi) << 16);
}
__device__ __forceinline__ float bfback(float x) {  // RNE16(x) as f32
  return __uint_as_float(bf16rne(x) << 16);
}
// lo-residual pair: RNE16(x - RNE16(x))
__device__ __forceinline__ unsigned bf2lo(float x, float y) {
  return bf2(x - bfback(x), y - bfback(y));
}
// Monotone f32->u32: unsigned compare == float compare (total order).
__device__ __forceinline__ unsigned mono(float f) {
  unsigned u = __float_as_uint(f);
  return u ^ ((unsigned)((int)u >> 31) | 0x80000000u);
}
__device__ __forceinline__ u64 u64min(u64 a, u64 b) { return a < b ? a : b; }

// Prep: codebook -> fragment-major HI and LO bf16 sets + csq.
__global__ __launch_bounds__(256) void vq_prep_kernel(
    const float* __restrict__ cb, uint4* __restrict__ cb_frag,
    float* __restrict__ csqg) {
  const int gid = blockIdx.x * 256 + threadIdx.x;
  if (gid < 4096) {                       // 16 RT x 4 s x 64 lanes
    const int f = gid >> 6, lane = gid & 63;
    const int RT = f >> 2, s = f & 3;
    const int row = RT * 32 + (lane & 31);
    const float4* src =
        reinterpret_cast<const float4*>(cb + (size_t)row * DIM + s * 16 + (lane >> 5) * 8);
    const float4 a = src[0], b = src[1];
    cb_frag[gid] = make_uint4(bf2(a.x, a.y), bf2(a.z, a.w), bf2(b.x, b.y), bf2(b.z, b.w));
    cb_frag[4096 + gid] =
        make_uint4(bf2lo(a.x, a.y), bf2lo(a.z, a.w), bf2lo(b.x, b.y), bf2lo(b.z, b.w));
  } else if (gid < 4096 + KCB) {
    const int k = gid - 4096;
    const float4* r4 = reinterpret_cast<const float4*>(cb + (size_t)k * DIM);
    float s = 0.f;
#pragma unroll
    for (int i = 0; i < 16; ++i) {
      float4 c = r4[i];
      s = fmaf(c.x, c.x, s); s = fmaf(c.y, c.y, s);
      s = fmaf(c.z, c.z, s); s = fmaf(c.w, c.w, s);
    }
    csqg[k] = s;
  }
}

// Single-pass split-precision certified argmin + fused gather.
// dot = hiA*hiB + loA*hiB (acc0) + hiA*loB (acc1): |S - S_f32| <= marg/3.
// Pass A tracks (m1,k1,m2) online; margin-resolved tokens (~99.8%) are
// FINAL. Unresolved -> BLOCK-COOPERATIVE exact f32 scan (each thread scores
// 2 rows; no serial 512-loop — round-13's straggler-block poison).
__global__ __launch_bounds__(256, 4) void vq_argmin_kernel(
    const float* __restrict__ cb,
    const float* __restrict__ emb,
    const uint4* __restrict__ cb_frag,
    const float* __restrict__ csqg,
    float* __restrict__ out) {
  __shared__ char  etile[TPB * 128];     // 4 KB swizzled bf16 hi tokens
  __shared__ char  etilo[TPB * 128];     // 4 KB swizzled bf16 lo tokens
  __shared__ float ef32[TPB][DIM];       // 8 KB f32 tokens (phase-C broadcast)
  __shared__ float csq_l[KCB];           // 2 KB
  __shared__ float esq_p[256];           // 1 KB (8 partials per token)
  __shared__ float mA[4][TPB];           // per-wave m1
  __shared__ float mB[4][TPB];           // per-wave m2
  __shared__ int   kA[4][TPB];           // per-wave k1
  __shared__ int   sel[TPB];
  __shared__ int   nU;
  __shared__ short uList[TPB];
  __shared__ u64   uredW[4];

  const int tid  = threadIdx.x;
  const int lane = tid & 63;
  const int w    = tid >> 6;
  const int col  = lane & 31;            // token within block
  const int half = lane >> 5;
  const int blk  = blockIdx.x;

  if (tid == 0) nU = 0;

  // ---- stage 32 tokens: 8 f32/thread -> {f32 LDS, hi+lo bf16 swizzled} ----
  {
    const float4* ep4 = reinterpret_cast<const float4*>(emb + (size_t)blk * TPB * DIM);
    const float4 v0 = ep4[tid * 2 + 0], v1 = ep4[tid * 2 + 1];
    float ss = 0.f;
    ss = fmaf(v0.x, v0.x, ss); ss = fmaf(v0.y, v0.y, ss);
    ss = fmaf(v0.z, v0.z, ss); ss = fmaf(v0.w, v0.w, ss);
    ss = fmaf(v1.x, v1.x, ss); ss = fmaf(v1.y, v1.y, ss);
    ss = fmaf(v1.z, v1.z, ss); ss = fmaf(v1.w, v1.w, ss);
    esq_p[tid] = ss;
    float4* ed = reinterpret_cast<float4*>(&ef32[tid >> 3][(tid & 7) * 8]);
    ed[0] = v0; ed[1] = v1;
    const int tok = tid >> 3, c0 = tid & 7;        // 16B bf16 chunk c0
    const int a0 = tok * 128 + ((16 * c0) ^ ((tok & 7) << 4));
    *reinterpret_cast<uint4*>(etile + a0) =
        make_uint4(bf2(v0.x, v0.y), bf2(v0.z, v0.w), bf2(v1.x, v1.y), bf2(v1.z, v1.w));
    *reinterpret_cast<uint4*>(etilo + a0) =
        make_uint4(bf2lo(v0.x, v0.y), bf2lo(v0.z, v0.w), bf2lo(v1.x, v1.y), bf2lo(v1.z, v1.w));
  }
  if (tid < 128)
    reinterpret_cast<float4*>(csq_l)[tid] = reinterpret_cast<const float4*>(csqg)[tid];
  __syncthreads();                                          // barrier 1

  // ---- B-fragment preload: hi + lo (8 ds_read_b128 per lane) ----
  s16x8 Bh[4], Bl[4];
#pragma unroll
  for (int s = 0; s < 4; ++s) {
    const int c = 2 * s + half;
    const int a = col * 128 + ((16 * c) ^ ((col & 7) << 4));
    Bh[s] = *reinterpret_cast<const s16x8*>(etile + a);
    Bl[s] = *reinterpret_cast<const s16x8*>(etilo + a);
  }

  const int rowbase = w * 128;
  const s16x8* frag = reinterpret_cast<const s16x8*>(cb_frag);
  const s16x8* fragLo = frag + 4096;

  // ---- Pass A: split MFMA -> online (m1,k1,m2); accs die per tile ----
  float m1 = 3.4e38f, m2 = 3.4e38f;
  int k1 = 0;
#pragma unroll 1
  for (int rt = 0; rt < 4; ++rt) {
    const int fb = ((w * 4 + rt) * 4) * 64 + lane;
    f32x16 a0 = {}, a1 = {};                 // 2 accs break the MFMA chain
#pragma unroll
    for (int s = 0; s < 4; ++s) {
      const s16x8 Ah = frag[fb + s * 64];    // streamed, dies after 2 MFMAs
      a0 = __builtin_amdgcn_mfma_f32_32x32x16_bf16(Ah, Bh[s], a0, 0, 0, 0);
      a1 = __builtin_amdgcn_mfma_f32_32x32x16_bf16(Ah, Bl[s], a1, 0, 0, 0);
      const s16x8 Al = fragLo[fb + s * 64];
      a0 = __builtin_amdgcn_mfma_f32_32x32x16_bf16(Al, Bh[s], a0, 0, 0, 0);
    }
    const int rb = rowbase + rt * 32 + 4 * half;
#pragma unroll
    for (int gq = 0; gq < 4; ++gq) {
      const float4 cs = *reinterpret_cast<const float4*>(&csq_l[rb + 8 * gq]);
#pragma unroll
      for (int e = 0; e < 4; ++e) {
        const float c = (e == 0) ? cs.x : (e == 1) ? cs.y : (e == 2) ? cs.z : cs.w;
        const float S = fmaf(-2.f, a0[gq * 4 + e], fmaf(-2.f, a1[gq * 4 + e], c));
        const float tmx = fmaxf(m1, S);      // m2 update BEFORE m1
        m2 = fminf(m2, tmx);
        const bool lt = S < m1;              // k ascends: strict < keeps low k
        k1 = lt ? (rb + 8 * gq + e) : k1;
        m1 = fminf(m1, S);
      }
    }
  }
  // wave-half merge (halves interleave rows: explicit k tie-break)
  {
    const float m1o = __shfl_xor(m1, 32);
    const float m2o = __shfl_xor(m2, 32);
    const int k1o = __shfl_xor(k1, 32);
    const float tmx = fmaxf(m1, m1o);
    m2 = fminf(fminf(m2, m2o), tmx);
    const bool better = (m1o < m1) || (m1o == m1 && k1o < k1);
    k1 = better ? k1o : k1;
    m1 = fminf(m1, m1o);
  }
  if (lane < 32) { mA[w][col] = m1; mB[w][col] = m2; kA[w][col] = k1; }
  __syncthreads();                                          // barrier 2

  // ---- block merge + margin certification (tid<TPB only) ----
  if (tid < TPB) {
    float bm1 = mA[0][tid], bm2 = mB[0][tid];
    int bk = kA[0][tid];
#pragma unroll
    for (int w2 = 1; w2 < 4; ++w2) {
      const float om1 = mA[w2][tid], om2 = mB[w2][tid];
      const int ok = kA[w2][tid];
      const float tmx = fmaxf(bm1, om1);
      bm2 = fminf(fminf(bm2, om2), tmx);
      if (om1 < bm1) bk = ok;                // disjoint ascending k ranges
      bm1 = fminf(bm1, om1);
    }
    const float esq = ((esq_p[tid * 8 + 0] + esq_p[tid * 8 + 1]) +
                      (esq_p[tid * 8 + 2] + esq_p[tid * 8 + 3])) +
                      ((esq_p[tid * 8 + 4] + esq_p[tid * 8 + 5]) +
                      (esq_p[tid * 8 + 6] + esq_p[tid * 8 + 7]));
    const float marg = 1e-4f * sqrtf(esq) + 1e-5f;   // ~3x the true 2B bound
    sel[tid] = bk;
    if ((bm2 - bm1) > marg) {
      out[(size_t)2 * N_TOK * DIM + blk * TPB + tid] = (float)bk;
    } else {
      const int p = atomicAdd(&nU, 1);
      uList[p] = (short)tid;
    }
  }
  __syncthreads();                                          // barrier 3

  // ---- Phase C (rare): block-cooperative exact f32 scan per unresolved ----
  // 256 threads x 2 rows = 512 rows in parallel; ~1-2us per token.
  for (int u = 0; u < nU; ++u) {
    const int t = uList[u];
    const float4* e4 = reinterpret_cast<const float4*>(&ef32[t][0]);  // broadcast
    u64 bb = ~0ull;
#pragma unroll
    for (int r = 0; r < 2; ++r) {
      const int k = 2 * tid + r;
      const float4* c4 = reinterpret_cast<const float4*>(cb + (size_t)k * DIM);
      float s0 = 0.f, s1 = 0.f, s2 = 0.f, s3 = 0.f;
#pragma unroll
      for (int i = 0; i < 16; ++i) {
        const float4 c = c4[i], e = e4[i];
        s0 = fmaf(c.x, e.x, s0);
        s1 = fmaf(c.y, e.y, s1);
        s2 = fmaf(c.z, e.z, s2);
        s3 = fmaf(c.w, e.w, s3);
      }
      const float S = fmaf(-2.f, (s0 + s1) + (s2 + s3), csq_l[k]);
      bb = u64min(bb, ((u64)mono(S) << 32) | (unsigned)k);
    }
#pragma unroll
    for (int off = 32; off; off >>= 1)
      bb = u64min(bb, __shfl_xor(bb, off));
    if (lane == 0) uredW[w] = bb;
    __syncthreads();
    if (tid == 0) {
      const u64 b = u64min(u64min(uredW[0], uredW[1]), u64min(uredW[2], uredW[3]));
      const int idx = (int)(unsigned)(b & 0xFFFFFFFFull);
      sel[t] = idx;
      out[(size_t)2 * N_TOK * DIM + blk * TPB + t] = (float)idx;
    }
    __syncthreads();
  }
  __syncthreads();                                          // barrier 4

  // ---- Phase D: fused gather-write of both quantized sections ----
  {
    const float4* cb4 = reinterpret_cast<const float4*>(cb);
    float4* out4 = reinterpret_cast<float4*>(out);
#pragma unroll
    for (int mm = 0; mm < 2; ++mm) {
      const int i = tid + 256 * mm;
      const int t = i >> 4, j = i & 15;
      const float4 v = cb4[sel[t] * (DIM / 4) + j];
      const size_t g = (size_t)(blk * TPB + t) * (DIM / 4) + j;
      out4[g] = v;
      out4[(size_t)N_TOK * (DIM / 4) + g] = v;
    }
  }
}

extern "C" void kernel_launch(void* const* d_in, const int* in_sizes, int n_in,
                              void* d_out, int out_size, void* d_ws, size_t ws_size,
                              hipStream_t stream) {
  const float* cb  = (const float*)d_in[0];   // (512, 64) f32
  const float* emb = (const float*)d_in[1];   // (65536, 1, 64) f32
  float* out = (float*)d_out;
  uint4* cb_frag = (uint4*)d_ws;                            // 128 KB hi+lo fragments
  float* csqg = (float*)((char*)d_ws + 131072);             // 2 KB csq

  vq_prep_kernel<<<18, 256, 0, stream>>>(cb, cb_frag, csqg);
  vq_argmin_kernel<<<N_TOK / TPB, 256, 0, stream>>>(cb, emb, cb_frag, csqg, out);
}

// Round 16
// 27.290 us; speedup vs baseline: 4.6242x; 1.5999x over previous
//
#include <hip/hip_runtime.h>
#include <hip/hip_bf16.h>

#define N_TOK 65536
#define KCB   512
#define DIM   64
#define TPB   32    // tokens per block
#define CAP   16    // per-token candidate capacity (overflow -> full rescan)

typedef __attribute__((ext_vector_type(4)))  float f32x4;
typedef __attribute__((ext_vector_type(8)))  short s16x8;
typedef __attribute__((ext_vector_type(16))) float f32x16;
typedef unsigned long long u64;

__device__ __forceinline__ unsigned bf16rne(float f) {
  unsigned u = __float_as_uint(f);
  return (u + 0x7FFFu + ((u >> 16) & 1u)) >> 16;   // round-to-nearest-even
}
__device__ __forceinline__ unsigned bf2(float lo, float hi) {
  return bf16rne(lo) | (bf16rne(hi) << 16);
}
// Monotone f32->u32: unsigned compare == float compare (total order).
__device__ __forceinline__ unsigned mono(float f) {
  unsigned u = __float_as_uint(f);
  return u ^ ((unsigned)((int)u >> 31) | 0x80000000u);
}
__device__ __forceinline__ u64 u64min(u64 a, u64 b) { return a < b ? a : b; }

// Exact f32 score of row k for an 8-lane group's token (INLINE — no ABI).
// Each sublane covers 8 elements; 3x shfl_xor completes the 64-dot.
__device__ __forceinline__ u64 group_score8(
    const float* __restrict__ cb, const float* __restrict__ erow,
    const float* __restrict__ csql, int k, int sub) {
  const float4* c4 = reinterpret_cast<const float4*>(cb + (size_t)k * DIM + sub * 8);
  const float4* e4 = reinterpret_cast<const float4*>(erow);
  const float4 c0 = c4[0], c1 = c4[1], e0 = e4[0], e1 = e4[1];
  float s0 = 0.f, s1 = 0.f;
  s0 = fmaf(c0.x, e0.x, s0); s1 = fmaf(c0.y, e0.y, s1);
  s0 = fmaf(c0.z, e0.z, s0); s1 = fmaf(c0.w, e0.w, s1);
  s0 = fmaf(c1.x, e1.x, s0); s1 = fmaf(c1.y, e1.y, s1);
  s0 = fmaf(c1.z, e1.z, s0); s1 = fmaf(c1.w, e1.w, s1);
  float p = s0 + s1;
  p += __shfl_xor(p, 1);
  p += __shfl_xor(p, 2);
  p += __shfl_xor(p, 4);
  const float S = fmaf(-2.f, p, csql[k]);
  return ((u64)mono(S) << 32) | (unsigned)k;
}

// Prep: codebook -> FRAGMENT-MAJOR bf16 layout + csq.
__global__ __launch_bounds__(256) void vq_prep_kernel(
    const float* __restrict__ cb, uint4* __restrict__ cb_frag,
    float* __restrict__ csqg) {
  const int gid = blockIdx.x * 256 + threadIdx.x;
  if (gid < 4096) {                       // 16 RT x 4 s x 64 lanes
    const int f = gid >> 6, lane = gid & 63;
    const int RT = f >> 2, s = f & 3;
    const int row = RT * 32 + (lane & 31);
    const float4* src =
        reinterpret_cast<const float4*>(cb + (size_t)row * DIM + s * 16 + (lane >> 5) * 8);
    const float4 a = src[0], b = src[1];
    cb_frag[gid] = make_uint4(bf2(a.x, a.y), bf2(a.z, a.w), bf2(b.x, b.y), bf2(b.z, b.w));
  } else if (gid < 4096 + KCB) {
    const int k = gid - 4096;
    const float4* r4 = reinterpret_cast<const float4*>(cb + (size_t)k * DIM);
    float s = 0.f;
#pragma unroll
    for (int i = 0; i < 16; ++i) {
      float4 c = r4[i];
      s = fmaf(c.x, c.x, s); s = fmaf(c.y, c.y, s);
      s = fmaf(c.z, c.z, s); s = fmaf(c.w, c.w, s);
    }
    csqg[k] = s;
  }
}

// Fused certified argmin + gather (round-10 structure, best measured: 31us).
// 2048 blocks x 32 tokens; 4 waves each owning 128 rows. Pass A: MFMA ->
// running min. Pass B: bit-identical recompute -> LDS candidate lists.
// Phase C: 8 lanes/token exact-f32 rescore. Phase D: gather-write.
// Round-16 delta: ALL output stores NON-TEMPORAL (via ext_vector f32x4 —
// HIP float4 is rejected by the builtin). The 33.6MB write stream is never
// re-read and evicts the L2-hot cb_frag/cb/csq working set.
__global__ __launch_bounds__(256, 6) void vq_argmin_kernel(
    const float* __restrict__ cb,
    const float* __restrict__ emb,
    const uint4* __restrict__ cb_frag,
    const float* __restrict__ csqg,
    float* __restrict__ out) {
  __shared__ float ef32[TPB * DIM];      // 8 KB f32 tokens
  __shared__ char  etile[TPB * 128];     // 4 KB swizzled bf16 tokens
  __shared__ float csq_l[KCB];           // 2 KB
  __shared__ float esq_p[256];           // 1 KB (8 partials per token)
  __shared__ float m_red[4][TPB];
  __shared__ int   cnt[TPB];
  __shared__ short list[TPB][CAP];
  __shared__ int   sel[TPB];

  const int tid  = threadIdx.x;
  const int lane = tid & 63;
  const int w    = tid >> 6;
  const int col  = lane & 31;            // token within block
  const int half = lane >> 5;
  const int blk  = blockIdx.x;

  if (tid < TPB) cnt[tid] = 0;

  // ---- stage 32 tokens: 8 f32/thread -> {f32 LDS, RNE-bf16 swizzled} ----
  {
    const float4* ep4 = reinterpret_cast<const float4*>(emb + (size_t)blk * TPB * DIM);
    const float4 v0 = ep4[tid * 2 + 0], v1 = ep4[tid * 2 + 1];
    float ss = 0.f;
    ss = fmaf(v0.x, v0.x, ss); ss = fmaf(v0.y, v0.y, ss);
    ss = fmaf(v0.z, v0.z, ss); ss = fmaf(v0.w, v0.w, ss);
    ss = fmaf(v1.x, v1.x, ss); ss = fmaf(v1.y, v1.y, ss);
    ss = fmaf(v1.z, v1.z, ss); ss = fmaf(v1.w, v1.w, ss);
    esq_p[tid] = ss;
    float4* ed = reinterpret_cast<float4*>(ef32);
    ed[tid * 2 + 0] = v0;
    ed[tid * 2 + 1] = v1;
    const int tok = tid >> 3, c0 = tid & 7;        // 16B bf16 chunk c0
    const int a0 = tok * 128 + ((16 * c0) ^ ((tok & 7) << 4));
    *reinterpret_cast<uint4*>(etile + a0) =
        make_uint4(bf2(v0.x, v0.y), bf2(v0.z, v0.w), bf2(v1.x, v1.y), bf2(v1.z, v1.w));
  }
  if (tid < 128)
    reinterpret_cast<float4*>(csq_l)[tid] = reinterpret_cast<const float4*>(csqg)[tid];
  __syncthreads();                                          // barrier 1

  // ---- B-fragment preload (4 ds_read_b128 per lane) ----
  s16x8 Bf[4];
#pragma unroll
  for (int s = 0; s < 4; ++s) {
    const int c = 2 * s + half;
    const int a = col * 128 + ((16 * c) ^ ((col & 7) << 4));
    Bf[s] = *reinterpret_cast<const s16x8*>(etile + a);
  }

  const int rowbase = w * 128;
  const s16x8* frag = reinterpret_cast<const s16x8*>(cb_frag);

  // ---- Pass A: MFMA -> per-row-tile mins + running min (16 accs live) ----
  float gmin[4];
  float m = 3.4e38f;
#pragma unroll
  for (int rt = 0; rt < 4; ++rt) {
    f32x16 a0 = {};
#pragma unroll
    for (int s = 0; s < 4; ++s) {
      const s16x8 Af = frag[((w * 4 + rt) * 4 + s) * 64 + lane];  // coalesced 1KB
      a0 = __builtin_amdgcn_mfma_f32_32x32x16_bf16(Af, Bf[s], a0, 0, 0, 0);
    }
    const int rb = rowbase + rt * 32 + 4 * half;
    float g = 3.4e38f;
#pragma unroll
    for (int gq = 0; gq < 4; ++gq) {
      const float4 cs = *reinterpret_cast<const float4*>(&csq_l[rb + 8 * gq]);
#pragma unroll
      for (int e = 0; e < 4; ++e) {
        const float c = (e == 0) ? cs.x : (e == 1) ? cs.y : (e == 2) ? cs.z : cs.w;
        g = fminf(g, fmaf(-2.f, a0[gq * 4 + e], c));
      }
    }
    gmin[rt] = g;
    m = fminf(m, g);
  }
  m = fminf(m, __shfl_xor(m, 32));
  if (lane < 32) m_red[w][col] = m;
  __syncthreads();                                          // barrier 2

  // thr = min_w(m) + 2*B_t (redundant per-lane; no serial section).
  // B_t bounds |S_bf16 - S_f32| for RNE operands; certified rounds 6-10.
  float thr;
  {
    const float esq = ((esq_p[col * 8 + 0] + esq_p[col * 8 + 1]) +
                       (esq_p[col * 8 + 2] + esq_p[col * 8 + 3])) +
                      ((esq_p[col * 8 + 4] + esq_p[col * 8 + 5]) +
                       (esq_p[col * 8 + 6] + esq_p[col * 8 + 7]));
    const float mt = fminf(fminf(m_red[0][col], m_red[1][col]),
                           fminf(m_red[2][col], m_red[3][col]));
    thr = mt + 0.0328f * sqrtf(esq) + 2e-4f;
  }

  // ---- Pass B: bit-identical recompute of surviving tiles -> LDS lists ----
#pragma unroll
  for (int rt = 0; rt < 4; ++rt) {
    if (!__any(gmin[rt] <= thr)) continue;
    f32x16 a0 = {};
#pragma unroll
    for (int s = 0; s < 4; ++s) {
      const s16x8 Af = frag[((w * 4 + rt) * 4 + s) * 64 + lane];
      a0 = __builtin_amdgcn_mfma_f32_32x32x16_bf16(Af, Bf[s], a0, 0, 0, 0);
    }
    const int rb = rowbase + rt * 32 + 4 * half;
#pragma unroll
    for (int gq = 0; gq < 4; ++gq) {
      const float4 cs = *reinterpret_cast<const float4*>(&csq_l[rb + 8 * gq]);
#pragma unroll
      for (int e = 0; e < 4; ++e) {
        const float c = (e == 0) ? cs.x : (e == 1) ? cs.y : (e == 2) ? cs.z : cs.w;
        if (fmaf(-2.f, a0[gq * 4 + e], c) <= thr) {
          const int p = atomicAdd(&cnt[col], 1);
          if (p < CAP) list[col][p] = (short)(rb + 8 * gq + e);
        }
      }
    }
  }
  __syncthreads();                                          // barrier 3

  // ---- Phase C: 8 lanes per token, inline exact-f32 rescore ----
  {
    const int t = tid >> 3, sub = tid & 7;
    const int nc = cnt[t];
    const float* erow = ef32 + t * DIM + sub * 8;
    u64 bb = ~0ull;
    if (nc <= CAP) {
      for (int i = 0; i < nc; ++i)
        bb = u64min(bb, group_score8(cb, erow, csq_l, list[t][i], sub));
    } else {
      // overflow (adversarial data only): full exact scan, still correct
      for (int k = 0; k < KCB; ++k)
        bb = u64min(bb, group_score8(cb, erow, csq_l, k, sub));
    }
    if (sub == 0) {
      const int idx = (int)(unsigned)(bb & 0xFFFFFFFFull);
      sel[t] = idx;
      __builtin_nontemporal_store(
          (float)idx, &out[(size_t)2 * N_TOK * DIM + blk * TPB + t]);
    }
  }
  __syncthreads();                                          // barrier 4

  // ---- Phase D: fused gather-write of both quantized sections (NT) ----
  {
    const float4* cb4 = reinterpret_cast<const float4*>(cb);
    f32x4* out4 = reinterpret_cast<f32x4*>(out);
#pragma unroll
    for (int mm = 0; mm < 2; ++mm) {
      const int i = tid + 256 * mm;
      const int t = i >> 4, j = i & 15;
      const float4 v = cb4[sel[t] * (DIM / 4) + j];
      const f32x4 vv = {v.x, v.y, v.z, v.w};
      const size_t g = (size_t)(blk * TPB + t) * (DIM / 4) + j;
      __builtin_nontemporal_store(vv, &out4[g]);
      __builtin_nontemporal_store(vv, &out4[(size_t)N_TOK * (DIM / 4) + g]);
    }
  }
}

extern "C" void kernel_launch(void* const* d_in, const int* in_sizes, int n_in,
                              void* d_out, int out_size, void* d_ws, size_t ws_size,
                              hipStream_t stream) {
  const float* cb  = (const float*)d_in[0];   // (512, 64) f32
  const float* emb = (const float*)d_in[1];   // (65536, 1, 64) f32
  float* out = (float*)d_out;
  uint4* cb_frag = (uint4*)d_ws;                               // 64 KB fragment-major bf16
  float* csqg = (float*)((char*)d_ws + (size_t)KCB * DIM * 2); // 2 KB csq

  vq_prep_kernel<<<18, 256, 0, stream>>>(cb, cb_frag, csqg);
  vq_argmin_kernel<<<N_TOK / TPB, 256, 0, stream>>>(cb, emb, cb_frag, csqg, out);
}